// Round 1
// baseline (561.631 us; speedup 1.0000x reference)
//
#include <hip/hip_runtime.h>
#include <cstddef>

#define CC   128
#define AD   16
#define VD   64
#define HWN  4096
#define PJ   1024
#define NB   8

// ---------------------------------------------------------------------------
// Kernel 1: fused transpose-free QKV projection + 2x2 maxpool for K,V.
// Grid: (32 tiles, 8 batches), block 256. Tile = 2 image rows = 128 contiguous
// positions. x tile staged in LDS as xL[c][p] (reads are p-fixed per lane ->
// broadcast / distinct-bank, conflict-free).
// ---------------------------------------------------------------------------
__global__ __launch_bounds__(256) void k_proj_pool(
    const float* __restrict__ x,
    const float* __restrict__ Wq, const float* __restrict__ bq,
    const float* __restrict__ Wk, const float* __restrict__ bk,
    const float* __restrict__ Wv, const float* __restrict__ bv,
    float* __restrict__ qws,   // (8,4096,16)
    float* __restrict__ Kp,    // (8,1024,16)  Kp[n][j][d]
    float* __restrict__ Vp)    // (8,1024,64)  Vp[n][j][dv]
{
    __shared__ float xL[CC][128];
    const int tile = blockIdx.x;       // 0..31 (pooled row)
    const int n    = blockIdx.y;
    const int t    = threadIdx.x;
    const int p0   = tile * 128;       // first flat position of the strip
    const float* xb = x + (size_t)n * CC * HWN;

    // ---- load 128 channels x 128 positions, coalesced float4 ----
    {
        const int r0 = t >> 5;         // 0..7
        const int v4 = t & 31;         // 0..31
        for (int it = 0; it < 16; ++it) {
            const int c = r0 + it * 8;
            const float4 val = *(const float4*)(xb + (size_t)c * HWN + p0 + v4 * 4);
            *(float4*)&xL[c][v4 * 4] = val;
        }
    }
    __syncthreads();

    const float4* Wq4 = (const float4*)Wq;  const float4* bq4 = (const float4*)bq;
    const float4* Wk4 = (const float4*)Wk;  const float4* bk4 = (const float4*)bk;
    const float4* Wv4 = (const float4*)Wv;  const float4* bv4 = (const float4*)bv;

    // ---- Q: 128 positions x 4 float4-groups of d ----
    {
        float4* qo = (float4*)(qws + ((size_t)n * HWN + p0) * AD);
        for (int i = 0; i < 2; ++i) {
            const int idx = t + 256 * i;      // 0..511
            const int p = idx >> 2, dg = idx & 3;
            float4 acc = bq4[dg];
            for (int c = 0; c < CC; ++c) {
                const float xv = xL[c][p];
                const float4 w = Wq4[c * 4 + dg];
                acc.x += xv * w.x; acc.y += xv * w.y;
                acc.z += xv * w.z; acc.w += xv * w.w;
            }
            qo[p * 4 + dg] = acc;
        }
    }

    // ---- K pooled: 32 quads x 4 float4-groups of d (128 work items) ----
    if (t < 128) {
        const int quad = t >> 2, dg = t & 3;
        float4 m = make_float4(-1e30f, -1e30f, -1e30f, -1e30f);
        for (int pp = 0; pp < 4; ++pp) {
            const int pl = (pp >> 1) * 64 + quad * 2 + (pp & 1);
            float4 acc = make_float4(0.f, 0.f, 0.f, 0.f);
            for (int c = 0; c < CC; ++c) {
                const float xv = xL[c][pl];
                const float4 w = Wk4[c * 4 + dg];
                acc.x += xv * w.x; acc.y += xv * w.y;
                acc.z += xv * w.z; acc.w += xv * w.w;
            }
            m.x = fmaxf(m.x, acc.x); m.y = fmaxf(m.y, acc.y);
            m.z = fmaxf(m.z, acc.z); m.w = fmaxf(m.w, acc.w);
        }
        const float4 b = bk4[dg];
        m.x += b.x; m.y += b.y; m.z += b.z; m.w += b.w;
        ((float4*)Kp)[((size_t)n * PJ + tile * 32 + quad) * 4 + dg] = m;
    }

    // ---- V pooled: 32 quads x 16 float4-groups of dv (512 work items) ----
    for (int i = 0; i < 2; ++i) {
        const int idx = t + 256 * i;          // 0..511
        const int quad = idx >> 4, dg = idx & 15;
        float4 m = make_float4(-1e30f, -1e30f, -1e30f, -1e30f);
        for (int pp = 0; pp < 4; ++pp) {
            const int pl = (pp >> 1) * 64 + quad * 2 + (pp & 1);
            float4 acc = make_float4(0.f, 0.f, 0.f, 0.f);
            for (int c = 0; c < CC; ++c) {
                const float xv = xL[c][pl];
                const float4 w = Wv4[c * 16 + dg];
                acc.x += xv * w.x; acc.y += xv * w.y;
                acc.z += xv * w.z; acc.w += xv * w.w;
            }
            m.x = fmaxf(m.x, acc.x); m.y = fmaxf(m.y, acc.y);
            m.z = fmaxf(m.z, acc.z); m.w = fmaxf(m.w, acc.w);
        }
        const float4 b = bv4[dg];
        m.x += b.x; m.y += b.y; m.z += b.z; m.w += b.w;
        ((float4*)Vp)[((size_t)n * PJ + tile * 32 + quad) * 16 + dg] = m;
    }
}

// ---------------------------------------------------------------------------
// Kernel 2: scores -> softmax -> attn@V -> out-proj -> residual.
// Grid: (512 q-tiles of 8 queries, 8 batches), block 256.
// ---------------------------------------------------------------------------
__global__ __launch_bounds__(256) void k_attn(
    const float* __restrict__ x,
    const float* __restrict__ qws,
    const float* __restrict__ Kp,
    const float* __restrict__ Vp,
    const float* __restrict__ Wo, const float* __restrict__ bo,
    const float* __restrict__ gamma,
    float* __restrict__ out)
{
    __shared__ float  S[8][1028];      // padded: breaks qi*1024 same-bank aliasing
    __shared__ float  qL[8][16];
    __shared__ float  lsum[8];
    __shared__ float4 aoP[256];
    __shared__ float  aoL[8][66];      // padded

    const int n  = blockIdx.y;
    const int q0 = blockIdx.x * 8;
    const int t  = threadIdx.x;

    if (t < 128) {
        const int qi = t >> 4, d = t & 15;
        qL[qi][d] = qws[((size_t)n * HWN + q0 + qi) * AD + d];
    }
    __syncthreads();

    // ---- scores: 8 x 1024, each a 16-dot; float4 K-row loads (coalesced) ----
    {
        const float4* Kp4 = (const float4*)(Kp + (size_t)n * PJ * AD);
        for (int i = 0; i < 32; ++i) {
            const int idx = t + 256 * i;       // 0..8191
            const int j = idx & 1023, qi = idx >> 10;
            const float4 k0 = Kp4[j * 4 + 0];
            const float4 k1 = Kp4[j * 4 + 1];
            const float4 k2 = Kp4[j * 4 + 2];
            const float4 k3 = Kp4[j * 4 + 3];
            const float* qq = qL[qi];
            float acc;
            acc  = k0.x * qq[0]  + k0.y * qq[1]  + k0.z * qq[2]  + k0.w * qq[3];
            acc += k1.x * qq[4]  + k1.y * qq[5]  + k1.z * qq[6]  + k1.w * qq[7];
            acc += k2.x * qq[8]  + k2.y * qq[9]  + k2.z * qq[10] + k2.w * qq[11];
            acc += k3.x * qq[12] + k3.y * qq[13] + k3.z * qq[14] + k3.w * qq[15];
            S[qi][j] = acc;
        }
    }
    __syncthreads();

    // ---- softmax: 32 lanes per row (stays inside wave halves for shfl_xor) ----
    {
        const int row = t >> 5, l = t & 31;
        float m = -1e30f;
        for (int j = l; j < 1024; j += 32) m = fmaxf(m, S[row][j]);
        for (int o = 16; o >= 1; o >>= 1) m = fmaxf(m, __shfl_xor(m, o));
        float s = 0.f;
        for (int j = l; j < 1024; j += 32) {
            const float e = __expf(S[row][j] - m);
            S[row][j] = e;
            s += e;
        }
        for (int o = 16; o >= 1; o >>= 1) s += __shfl_xor(s, o);
        if (l == 0) lsum[row] = s;
    }
    __syncthreads();

    // ---- attn @ V: items (qi, dv4) = 128, split j-range across thread halves ----
    {
        const float4* Vp4 = (const float4*)(Vp + (size_t)n * PJ * VD);
        const int item = t & 127, half = t >> 7;
        const int qi = item >> 4, dg = item & 15;
        const int jb = half * 512;
        float4 acc = make_float4(0.f, 0.f, 0.f, 0.f);
        for (int j = 0; j < 512; ++j) {
            const float p  = S[qi][jb + j];
            const float4 v = Vp4[(jb + j) * 16 + dg];
            acc.x += p * v.x; acc.y += p * v.y;
            acc.z += p * v.z; acc.w += p * v.w;
        }
        aoP[t] = acc;
    }
    __syncthreads();
    if (t < 128) {
        const int qi = t >> 4, dg = t & 15;
        const float4 a = aoP[t], b = aoP[t + 128];
        const float inv = 1.f / lsum[qi];
        aoL[qi][dg * 4 + 0] = (a.x + b.x) * inv;
        aoL[qi][dg * 4 + 1] = (a.y + b.y) * inv;
        aoL[qi][dg * 4 + 2] = (a.z + b.z) * inv;
        aoL[qi][dg * 4 + 3] = (a.w + b.w) * inv;
    }
    __syncthreads();

    // ---- out-proj + residual: 8 qi x 128 c ----
    {
        const float g = gamma[0];
        for (int i = 0; i < 4; ++i) {
            const int idx = t + 256 * i;       // 0..1023
            const int qi = idx & 7, c = idx >> 3;
            float acc = bo[c];
            for (int dv = 0; dv < VD; ++dv)
                acc += aoL[qi][dv] * Wo[dv * CC + c];
            const size_t off = ((size_t)n * CC + c) * HWN + q0 + qi;
            out[off] = x[off] + g * acc;
        }
    }
}

extern "C" void kernel_launch(void* const* d_in, const int* in_sizes, int n_in,
                              void* d_out, int out_size, void* d_ws, size_t ws_size,
                              hipStream_t stream) {
    const float* x     = (const float*)d_in[0];
    const float* Wq    = (const float*)d_in[1];
    const float* bq    = (const float*)d_in[2];
    const float* Wk    = (const float*)d_in[3];
    const float* bk    = (const float*)d_in[4];
    const float* Wv    = (const float*)d_in[5];
    const float* bv    = (const float*)d_in[6];
    const float* Wo    = (const float*)d_in[7];
    const float* bo    = (const float*)d_in[8];
    const float* gamma = (const float*)d_in[9];
    float* out = (float*)d_out;

    float* qws = (float*)d_ws;                          // 8*4096*16 = 524288 floats
    float* Kp  = qws + (size_t)NB * HWN * AD;           // 8*1024*16 = 131072 floats
    float* Vp  = Kp  + (size_t)NB * PJ  * AD;           // 8*1024*64 = 524288 floats
                                                        // total 4.5 MB of d_ws

    k_proj_pool<<<dim3(32, NB), 256, 0, stream>>>(x, Wq, bq, Wk, bk, Wv, bv,
                                                  qws, Kp, Vp);
    k_attn<<<dim3(512, NB), 256, 0, stream>>>(x, qws, Kp, Vp, Wo, bo, gamma, out);
}

// Round 2
// 513.012 us; speedup vs baseline: 1.0948x; 1.0948x over previous
//
#include <hip/hip_runtime.h>
#include <hip/hip_bf16.h>
#include <cstddef>

#define CC   128
#define AD   16
#define VD   64
#define HWN  4096
#define PJ   1024
#define NB   8

// bf16(bit-pair) -> 2 floats
__device__ inline float2 bf2f(unsigned v) {
    union { unsigned u; float f; } a, b;
    a.u = v << 16; b.u = v & 0xffff0000u;
    return make_float2(a.f, b.f);
}
__device__ inline unsigned short f2bf(float f) {
    union { float f; unsigned u; } a; a.f = f;
    unsigned r = a.u + 0x7fff + ((a.u >> 16) & 1);   // round-to-nearest-even
    return (unsigned short)(r >> 16);
}
__device__ inline float bf16f(unsigned short v) {
    union { unsigned u; float f; } a; a.u = ((unsigned)v) << 16;
    return a.f;
}

// ---------------------------------------------------------------------------
// Kernel 1: QKV projection + 2x2 maxpool.  Grid (32 tiles, 8 batch, 4 quarter),
// block 128 (= 2 image rows of 64).  Thread: 1 position x 1 channel-quarter
// (4 q + 4 k + 16 v accumulators).  x read direct from global (coalesced,
// L1/L2 reuse across quarters); W reads wave-uniform -> scalar loads.
// Outputs: qws fp32 (n,4096,16), Kt fp32 (n,16,1024) TRANSPOSED, Vp bf16
// (n,1024,64).
// ---------------------------------------------------------------------------
__global__ __launch_bounds__(128) void k_proj_pool(
    const float* __restrict__ x,
    const float* __restrict__ Wq, const float* __restrict__ bq,
    const float* __restrict__ Wk, const float* __restrict__ bk,
    const float* __restrict__ Wv, const float* __restrict__ bv,
    float* __restrict__ qws,
    float* __restrict__ Kt,
    unsigned short* __restrict__ Vp)
{
    __shared__ float          pk[128][5];    // k quarter, fp32, pad->5
    __shared__ unsigned short pv[128][18];   // v quarter, bf16, pad->18

    const int tile = blockIdx.x;     // 0..31  (2 image rows each)
    const int n    = blockIdx.y;
    const int qt   = blockIdx.z;     // channel quarter 0..3
    const int p    = threadIdx.x;    // 0..127 position in tile
    const int gp   = tile * 128 + p;
    const float* xb = x + (size_t)n * CC * HWN + gp;

    float qa[4], ka[4], va[16];
#pragma unroll
    for (int i = 0; i < 4; ++i) { qa[i] = bq[qt * 4 + i]; ka[i] = 0.f; }
#pragma unroll
    for (int i = 0; i < 16; ++i) va[i] = 0.f;

#pragma unroll 4
    for (int c = 0; c < CC; ++c) {
        const float xv = xb[(size_t)c * HWN];
        const float* wq = Wq + c * AD + qt * 4;
        const float* wk = Wk + c * AD + qt * 4;
        const float* wv = Wv + c * VD + qt * 16;
#pragma unroll
        for (int i = 0; i < 4; ++i)  qa[i] = fmaf(xv, wq[i], qa[i]);
#pragma unroll
        for (int i = 0; i < 4; ++i)  ka[i] = fmaf(xv, wk[i], ka[i]);
#pragma unroll
        for (int i = 0; i < 16; ++i) va[i] = fmaf(xv, wv[i], va[i]);
    }

    // q out (bias already in)
    {
        float4 v0 = make_float4(qa[0], qa[1], qa[2], qa[3]);
        *(float4*)(qws + ((size_t)n * HWN + gp) * AD + qt * 4) = v0;
    }

    // stash k (fp32) and v (bf16; round-then-max == max-then-round) for pooling
#pragma unroll
    for (int i = 0; i < 4; ++i)  pk[p][i] = ka[i];
#pragma unroll
    for (int i = 0; i < 16; ++i) pv[p][i] = f2bf(va[i]);
    __syncthreads();

    // pooled row index: tile covers image rows 2T,2T+1 -> pooled row T
    // quad for pooled col c2: positions {2c2, 2c2+1, 64+2c2, 64+2c2+1}
    // K: 4 d x 32 c2 = 128 items, one per thread
    {
        const int c2 = p & 31, dl = p >> 5;
        const int a = 2 * c2, b = 64 + 2 * c2;
        float m = fmaxf(fmaxf(pk[a][dl], pk[a + 1][dl]),
                        fmaxf(pk[b][dl], pk[b + 1][dl]));
        m += bk[qt * 4 + dl];
        Kt[((size_t)n * AD + qt * 4 + dl) * PJ + tile * 32 + c2] = m;
    }
    // V: 16 dv x 32 c2 = 512 items
#pragma unroll
    for (int it = 0; it < 4; ++it) {
        const int item = p + 128 * it;
        const int dvl = item & 15, c2 = item >> 4;
        const int a = 2 * c2, b = 64 + 2 * c2;
        float m = fmaxf(fmaxf(bf16f(pv[a][dvl]), bf16f(pv[a + 1][dvl])),
                        fmaxf(bf16f(pv[b][dvl]), bf16f(pv[b + 1][dvl])));
        m += bv[qt * 16 + dvl];
        Vp[((size_t)n * PJ + tile * 32 + c2) * VD + qt * 16 + dvl] = f2bf(m);
    }
}

// ---------------------------------------------------------------------------
// Kernel 2: scores -> softmax -> attn@V -> out-proj -> residual.
// Grid (512, 8), block 256, 8 queries/block.  K and V staged through a 32 KB
// LDS union buffer (shared across all 8 queries -> 8x less L2 traffic).
// ---------------------------------------------------------------------------
__global__ __launch_bounds__(256) void k_attn(
    const float* __restrict__ x,
    const float* __restrict__ qws,
    const float* __restrict__ Kt,            // (8,16,1024) fp32
    const unsigned short* __restrict__ Vp,   // (8,1024,64) bf16
    const float* __restrict__ Wo, const float* __restrict__ bo,
    const float* __restrict__ gamma,
    float* __restrict__ out)
{
    __shared__ float  S[8][1028];
    __shared__ float  buf[8192];     // union: Kt chunk [16][512] / V chunk [128][64]
    __shared__ float  qL[8][16];
    __shared__ float  lsum[8];
    __shared__ float4 aoP[256];
    __shared__ float  aoL[8][66];

    const int n  = blockIdx.y;
    const int q0 = blockIdx.x * 8;
    const int t  = threadIdx.x;

    if (t < 128) {
        const int qi = t >> 4, d = t & 15;
        qL[qi][d] = qws[((size_t)n * HWN + q0 + qi) * AD + d];
    }

    // ---- Phase A: scores, K in LDS (transposed layout -> stride-1 dots) ----
    const float4* Ksrc = (const float4*)(Kt + (size_t)n * AD * PJ);
    for (int ch = 0; ch < 2; ++ch) {
        // stage buf[16][512] <- Kt[:, ch*512 : ch*512+512]
#pragma unroll
        for (int it = 0; it < 8; ++it) {
            const int f = t + 256 * it;          // float4 index, 0..2047
            const int d = f >> 7, j4 = f & 127;
            ((float4*)buf)[d * 128 + j4] = Ksrc[d * 256 + ch * 128 + j4];
        }
        __syncthreads();
        // compute: 8 qi x 512 j items
#pragma unroll
        for (int it = 0; it < 16; ++it) {
            const int item = t + 256 * it;       // 0..4095
            const int j = item & 511, qi = item >> 9;
            const float* kc = buf + j;           // column, stride 512
            const float* qq = qL[qi];            // wave-uniform -> scalar
            float s = 0.f;
#pragma unroll
            for (int d = 0; d < AD; ++d) s = fmaf(qq[d], kc[d * 512], s);
            S[qi][ch * 512 + j] = s;
        }
        __syncthreads();
    }

    // ---- Phase B: softmax, 32 lanes per row ----
    {
        const int row = t >> 5, l = t & 31;
        float m = -1e30f;
        for (int j = l; j < 1024; j += 32) m = fmaxf(m, S[row][j]);
        for (int o = 16; o >= 1; o >>= 1) m = fmaxf(m, __shfl_xor(m, o));
        float s = 0.f;
        for (int j = l; j < 1024; j += 32) {
            const float e = __expf(S[row][j] - m);
            S[row][j] = e;
            s += e;
        }
        for (int o = 16; o >= 1; o >>= 1) s += __shfl_xor(s, o);
        if (l == 0) lsum[row] = s;
    }

    // ---- Phase C: attn @ V, V chunks (128 j) through LDS ----
    {
        const int item = t & 127, half = t >> 7;
        const int qi = item >> 4, dg = item & 15;
        float4 acc = make_float4(0.f, 0.f, 0.f, 0.f);
        const uint4* Vg = (const uint4*)(Vp + (size_t)n * PJ * VD);

        for (int ch = 0; ch < 8; ++ch) {
            __syncthreads();                     // buf free (also fences S after B)
            // stage: 128 rows x 64 dv, bf16 -> fp32
#pragma unroll
            for (int it = 0; it < 4; ++it) {
                const int idx = t + 256 * it;    // uint4 index, 0..1023 (8 bf16 each)
                const uint4 u = Vg[ch * 1024 + idx];
                float4* dst = (float4*)buf + idx * 2;
                const float2 e0 = bf2f(u.x), e1 = bf2f(u.y);
                const float2 e2 = bf2f(u.z), e3 = bf2f(u.w);
                dst[0] = make_float4(e0.x, e0.y, e1.x, e1.y);
                dst[1] = make_float4(e2.x, e2.y, e3.x, e3.y);
            }
            __syncthreads();
#pragma unroll
            for (int jj = 0; jj < 64; ++jj) {
                const int j = half * 64 + jj;
                const float p  = S[qi][ch * 128 + j];
                const float4 v = ((const float4*)buf)[j * 16 + dg];
                acc.x = fmaf(p, v.x, acc.x); acc.y = fmaf(p, v.y, acc.y);
                acc.z = fmaf(p, v.z, acc.z); acc.w = fmaf(p, v.w, acc.w);
            }
        }
        aoP[t] = acc;
    }
    __syncthreads();
    if (t < 128) {
        const int qi = t >> 4, dg = t & 15;
        const float4 a = aoP[t], b = aoP[t + 128];
        const float inv = 1.f / lsum[qi];
        aoL[qi][dg * 4 + 0] = (a.x + b.x) * inv;
        aoL[qi][dg * 4 + 1] = (a.y + b.y) * inv;
        aoL[qi][dg * 4 + 2] = (a.z + b.z) * inv;
        aoL[qi][dg * 4 + 3] = (a.w + b.w) * inv;
    }
    __syncthreads();

    // ---- out-proj + residual ----
    {
        const float g = gamma[0];
#pragma unroll
        for (int i = 0; i < 4; ++i) {
            const int idx = t + 256 * i;         // 0..1023
            const int qi = idx & 7, c = idx >> 3;
            float acc = bo[c];
#pragma unroll 8
            for (int dv = 0; dv < VD; ++dv)
                acc = fmaf(aoL[qi][dv], Wo[dv * CC + c], acc);
            const size_t off = ((size_t)n * CC + c) * HWN + q0 + qi;
            out[off] = x[off] + g * acc;
        }
    }
}

extern "C" void kernel_launch(void* const* d_in, const int* in_sizes, int n_in,
                              void* d_out, int out_size, void* d_ws, size_t ws_size,
                              hipStream_t stream) {
    const float* x     = (const float*)d_in[0];
    const float* Wq    = (const float*)d_in[1];
    const float* bq    = (const float*)d_in[2];
    const float* Wk    = (const float*)d_in[3];
    const float* bk    = (const float*)d_in[4];
    const float* Wv    = (const float*)d_in[5];
    const float* bv    = (const float*)d_in[6];
    const float* Wo    = (const float*)d_in[7];
    const float* bo    = (const float*)d_in[8];
    const float* gamma = (const float*)d_in[9];
    float* out = (float*)d_out;

    float* qws = (float*)d_ws;                                   // 2 MB fp32
    float* Kt  = qws + (size_t)NB * HWN * AD;                    // 512 KB fp32
    unsigned short* Vp = (unsigned short*)(Kt + (size_t)NB * AD * PJ);  // 1 MB bf16

    k_proj_pool<<<dim3(32, NB, 4), 128, 0, stream>>>(x, Wq, bq, Wk, bk, Wv, bv,
                                                     qws, Kt, Vp);
    k_attn<<<dim3(512, NB), 256, 0, stream>>>(x, qws, Kt, Vp, Wo, bo, gamma, out);
}

// Round 3
// 121.985 us; speedup vs baseline: 4.6041x; 4.2055x over previous
//
#include <hip/hip_runtime.h>
#include <cstddef>

#define CC   128
#define AD   16
#define VD   64
#define HWN  4096
#define PJ   1024
#define NB   8

typedef short short8 __attribute__((ext_vector_type(8)));
typedef float f32x4  __attribute__((ext_vector_type(4)));
typedef unsigned short u16;

__device__ inline u16 f2bf(float f) {
    union { float f; unsigned u; } a; a.f = f;
    unsigned r = a.u + 0x7fff + ((a.u >> 16) & 1);   // RNE
    return (u16)(r >> 16);
}
__device__ inline float bf16f(u16 v) {
    union { unsigned u; float f; } a; a.u = ((unsigned)v) << 16;
    return a.f;
}

// XOR-swizzled physical element index for bf16 LDS tiles (8-elem blocks).
// Guarantees conflict-free ds_read_b128 fragment reads (blk ^ row&7 tiles banks).
__device__ inline int ph128(int r, int c) { return r * 128 + ((((c >> 3) ^ (r & 7)) << 3) | (c & 7)); }
__device__ inline int ph64 (int r, int c) { return r * 64  + ((((c >> 3) ^ (r & 7)) << 3) | (c & 7)); }

// ---------------------------------------------------------------------------
// Kernel 1: QKV projection (MFMA GEMM, M=128 pos, K=128 ch, N=96) + 2x2 pool.
// Grid (32,8), block 256.  Outputs bf16: Qp(n,4096,16), Kp(n,1024,16),
// Vt(n,64,1024).
// ---------------------------------------------------------------------------
__global__ __launch_bounds__(256) void k_proj(
    const float* __restrict__ x,
    const float* __restrict__ Wq, const float* __restrict__ bq,
    const float* __restrict__ Wk, const float* __restrict__ bk,
    const float* __restrict__ Wv, const float* __restrict__ bv,
    u16* __restrict__ Qp, u16* __restrict__ Kp, u16* __restrict__ Vt)
{
    __shared__ __align__(16) u16 xT[128 * 128];   // x tile transposed; reused as out_lds
    __shared__ __align__(16) u16 WT[96 * 128];    // [n-dim][ch]

    const int tile = blockIdx.x, n = blockIdx.y, t = threadIdx.x;
    const int p0 = tile * 128;
    const int l = t & 63, w = t >> 6, g = l >> 4, lm = l & 15;

    // ---- stage x tile (coalesced float4 along HW) -> xT[pos][ch] bf16 ----
    {
        const float* xb = x + (size_t)n * CC * HWN + p0;
#pragma unroll
        for (int it = 0; it < 16; ++it) {
            const int idx = t + 256 * it;
            const int p4 = idx & 31, ch = idx >> 5;
            const float4 v = *(const float4*)(xb + (size_t)ch * HWN + p4 * 4);
            xT[ph128(p4 * 4 + 0, ch)] = f2bf(v.x);
            xT[ph128(p4 * 4 + 1, ch)] = f2bf(v.y);
            xT[ph128(p4 * 4 + 2, ch)] = f2bf(v.z);
            xT[ph128(p4 * 4 + 3, ch)] = f2bf(v.w);
        }
    }
    // ---- stage W^T: rows 0..15 = Wq, 16..31 = Wk, 32..95 = Wv ----
#pragma unroll
    for (int it = 0; it < 2; ++it) {
        const int idx = t + 256 * it;
        const int d4 = idx & 3, ch = idx >> 2;
        float4 v = *(const float4*)(Wq + ch * AD + d4 * 4);
        WT[ph128(d4 * 4 + 0, ch)] = f2bf(v.x);
        WT[ph128(d4 * 4 + 1, ch)] = f2bf(v.y);
        WT[ph128(d4 * 4 + 2, ch)] = f2bf(v.z);
        WT[ph128(d4 * 4 + 3, ch)] = f2bf(v.w);
        v = *(const float4*)(Wk + ch * AD + d4 * 4);
        WT[ph128(16 + d4 * 4 + 0, ch)] = f2bf(v.x);
        WT[ph128(16 + d4 * 4 + 1, ch)] = f2bf(v.y);
        WT[ph128(16 + d4 * 4 + 2, ch)] = f2bf(v.z);
        WT[ph128(16 + d4 * 4 + 3, ch)] = f2bf(v.w);
    }
#pragma unroll
    for (int it = 0; it < 8; ++it) {
        const int idx = t + 256 * it;
        const int d4 = idx & 15, ch = idx >> 4;
        const float4 v = *(const float4*)(Wv + ch * VD + d4 * 4);
        WT[ph128(32 + d4 * 4 + 0, ch)] = f2bf(v.x);
        WT[ph128(32 + d4 * 4 + 1, ch)] = f2bf(v.y);
        WT[ph128(32 + d4 * 4 + 2, ch)] = f2bf(v.z);
        WT[ph128(32 + d4 * 4 + 3, ch)] = f2bf(v.w);
    }
    __syncthreads();

    // ---- MFMA: wave w owns M-tiles {2w, 2w+1} x 6 N-tiles, K-loop 4x32 ----
    f32x4 acc[2][6];
#pragma unroll
    for (int i = 0; i < 2; ++i)
#pragma unroll
        for (int j = 0; j < 6; ++j) acc[i][j] = (f32x4){0.f, 0.f, 0.f, 0.f};
#pragma unroll
    for (int ks = 0; ks < 4; ++ks) {
        const short8 a0 = *(const short8*)&xT[ph128((w * 2 + 0) * 16 + lm, ks * 32 + g * 8)];
        const short8 a1 = *(const short8*)&xT[ph128((w * 2 + 1) * 16 + lm, ks * 32 + g * 8)];
#pragma unroll
        for (int nt = 0; nt < 6; ++nt) {
            const short8 b = *(const short8*)&WT[ph128(nt * 16 + lm, ks * 32 + g * 8)];
            acc[0][nt] = __builtin_amdgcn_mfma_f32_16x16x32_bf16(a0, b, acc[0][nt], 0, 0, 0);
            acc[1][nt] = __builtin_amdgcn_mfma_f32_16x16x32_bf16(a1, b, acc[1][nt], 0, 0, 0);
        }
    }
    __syncthreads();
    // ---- C-tiles -> out_lds[pos][nn] (reuse xT), C layout: row=g*4+r, col=lm
#pragma unroll
    for (int mt = 0; mt < 2; ++mt)
#pragma unroll
        for (int nt = 0; nt < 6; ++nt)
#pragma unroll
            for (int r = 0; r < 4; ++r)
                xT[ph128((w * 2 + mt) * 16 + g * 4 + r, nt * 16 + lm)] = f2bf(acc[mt][nt][r]);
    __syncthreads();

    // ---- Q store (+bq): rows=pos, cols 0..15 ----
    {
        const int pos = t >> 1, half = t & 1;
        const short8 s = *(const short8*)&xT[ph128(pos, half * 8)];
        u16 res[8];
#pragma unroll
        for (int j = 0; j < 8; ++j)
            res[j] = f2bf(bf16f((u16)s[j]) + bq[half * 8 + j]);
        *(uint4*)(Qp + (size_t)(n * HWN + p0 + pos) * AD + half * 8) = *(const uint4*)res;
    }
    // ---- K pool (+bk): cols 16..31 -> Kp[n][j][d] ----
#pragma unroll
    for (int it = 0; it < 2; ++it) {
        const int idx = t + 256 * it;
        const int c2 = idx >> 4, d = idx & 15;
        const float m = fmaxf(
            fmaxf(bf16f(xT[ph128(2 * c2,      16 + d)]), bf16f(xT[ph128(2 * c2 + 1,  16 + d)])),
            fmaxf(bf16f(xT[ph128(64 + 2 * c2, 16 + d)]), bf16f(xT[ph128(65 + 2 * c2, 16 + d)])));
        Kp[(size_t)(n * PJ + tile * 32 + c2) * AD + d] = f2bf(m + bk[d]);
    }
    // ---- V pool (+bv): cols 32..95 -> Vt[n][dv][j] (transposed) ----
    {
        const int dv = t >> 2, seg = t & 3;
        u16 res[8];
#pragma unroll
        for (int i = 0; i < 8; ++i) {
            const int c2 = seg * 8 + i;
            const float m = fmaxf(
                fmaxf(bf16f(xT[ph128(2 * c2,      32 + dv)]), bf16f(xT[ph128(2 * c2 + 1,  32 + dv)])),
                fmaxf(bf16f(xT[ph128(64 + 2 * c2, 32 + dv)]), bf16f(xT[ph128(65 + 2 * c2, 32 + dv)])));
            res[i] = f2bf(m + bv[dv]);
        }
        *(uint4*)(Vt + (size_t)(n * VD + dv) * PJ + tile * 32 + seg * 8) = *(const uint4*)res;
    }
}

// ---------------------------------------------------------------------------
// Kernel 2: flash attention + out-proj + residual, all MFMA.
// Grid (64,8), block 256 (4 waves x 16 q-rows = 64 q / block).
// ---------------------------------------------------------------------------
__global__ __launch_bounds__(256) void k_attn(
    const float* __restrict__ x,
    const u16* __restrict__ Qp, const u16* __restrict__ Kp, const u16* __restrict__ Vt,
    const float* __restrict__ Wo, const float* __restrict__ bo,
    const float* __restrict__ gma,
    float* __restrict__ out)
{
    __shared__ __align__(16) u16 smemA[128 * 16 + 64 * 128];  // K(2048) + V(8192); reused: WoT(8192)
    __shared__ __align__(16) u16 smemB[4 * 16 * 128];         // per-wave P; reused: per-wave O^T

    const int n = blockIdx.y, t = threadIdx.x;
    const int q0b = blockIdx.x * 64;
    const int l = t & 63, w = t >> 6, g = l >> 4, lm = l & 15;

    u16* Kl = smemA;          // [128 j][16 d], 2 blk/row, swizzle blk^(j&1)
    u16* Vl = smemA + 2048;   // [64 dv][128 j], ph128
    u16* Pl = smemB + w * 2048;

    // Q A-frag (lanes g>=2 are the K=16..31 zero pad)
    short8 qf = {0, 0, 0, 0, 0, 0, 0, 0};
    if (g < 2)
        qf = *(const short8*)(Qp + (size_t)(n * HWN + q0b + w * 16 + lm) * AD + g * 8);

    f32x4 O[4];
#pragma unroll
    for (int i = 0; i < 4; ++i) O[i] = (f32x4){0.f, 0.f, 0.f, 0.f};
    float mr[4] = {-1e30f, -1e30f, -1e30f, -1e30f};
    float lr[4] = {0.f, 0.f, 0.f, 0.f};

    for (int ch = 0; ch < 8; ++ch) {
        const int j0 = ch * 128;
        __syncthreads();
        // ---- stage K chunk (4 KB) ----
        {
            const int j = t >> 1, half = t & 1;
            const uint4 v = *(const uint4*)(Kp + (size_t)(n * PJ + j0 + j) * AD + half * 8);
            *(uint4*)&Kl[(j * 2 + (half ^ (j & 1))) * 8] = v;
        }
        // ---- stage V chunk (16 KB) ----
        {
            const int dv = t >> 2, seg = t & 3;
            const u16* src = Vt + (size_t)(n * VD + dv) * PJ + j0;
#pragma unroll
            for (int i = 0; i < 4; ++i) {
                const int jb = seg * 4 + i;
                const uint4 v = *(const uint4*)(src + jb * 8);
                *(uint4*)&Vl[(dv * 16 + (jb ^ (dv & 7))) * 8] = v;
            }
        }
        __syncthreads();

        // ---- scores: 8 j-tiles of 16, K=32 (d zero-padded) ----
        f32x4 S[8];
#pragma unroll
        for (int jt = 0; jt < 8; ++jt) {
            short8 kb = {0, 0, 0, 0, 0, 0, 0, 0};
            if (g < 2) {
                const int j = jt * 16 + lm;
                kb = *(const short8*)&Kl[(j * 2 + (g ^ (j & 1))) * 8];
            }
            const f32x4 z = (f32x4){0.f, 0.f, 0.f, 0.f};
            S[jt] = __builtin_amdgcn_mfma_f32_16x16x32_bf16(qf, kb, z, 0, 0, 0);
        }

        // ---- online softmax (C layout: row = g*4+r, col = jt*16+lm) ----
#pragma unroll
        for (int r = 0; r < 4; ++r) {
            float cm = S[0][r];
#pragma unroll
            for (int jt = 1; jt < 8; ++jt) cm = fmaxf(cm, S[jt][r]);
            cm = fmaxf(cm, __shfl_xor(cm, 1));
            cm = fmaxf(cm, __shfl_xor(cm, 2));
            cm = fmaxf(cm, __shfl_xor(cm, 4));
            cm = fmaxf(cm, __shfl_xor(cm, 8));
            const float nm = fmaxf(mr[r], cm);
            const float al = __expf(mr[r] - nm);
            mr[r] = nm;
            const int row = g * 4 + r;
            float sum = 0.f;
#pragma unroll
            for (int jt = 0; jt < 8; ++jt) {
                const float p = __expf(S[jt][r] - nm);
                sum += p;
                Pl[ph128(row, jt * 16 + lm)] = f2bf(p);
            }
            sum += __shfl_xor(sum, 1);
            sum += __shfl_xor(sum, 2);
            sum += __shfl_xor(sum, 4);
            sum += __shfl_xor(sum, 8);
            lr[r] = lr[r] * al + sum;
            O[0][r] *= al; O[1][r] *= al; O[2][r] *= al; O[3][r] *= al;
        }

        // ---- P @ V: P A-frags from per-wave LDS, V B-frags ----
#pragma unroll
        for (int ks = 0; ks < 4; ++ks) {
            const short8 pf = *(const short8*)&Pl[ph128(lm, ks * 32 + g * 8)];
#pragma unroll
            for (int dt = 0; dt < 4; ++dt) {
                const short8 vf = *(const short8*)&Vl[ph128(dt * 16 + lm, ks * 32 + g * 8)];
                O[dt] = __builtin_amdgcn_mfma_f32_16x16x32_bf16(pf, vf, O[dt], 0, 0, 0);
            }
        }
    }

    // ---- normalize, O^T -> per-wave LDS (B-frag source for out-proj) ----
    u16* Ol = smemB + w * 2048;   // reuse P region (per-wave, no barrier needed)
#pragma unroll
    for (int r = 0; r < 4; ++r) {
        const float inv = 1.f / lr[r];
        const int row = g * 4 + r;
#pragma unroll
        for (int dt = 0; dt < 4; ++dt)
            Ol[ph64(row, dt * 16 + lm)] = f2bf(O[dt][r] * inv);
    }
    __syncthreads();
    // ---- stage WoT[c][dv] bf16 into smemA (K/V dead now) ----
#pragma unroll
    for (int it = 0; it < 8; ++it) {
        const int idx = t + 256 * it;
        const int c4 = idx & 31, dv = idx >> 5;
        const float4 v = *(const float4*)(Wo + dv * CC + c4 * 4);
        smemA[ph64(c4 * 4 + 0, dv)] = f2bf(v.x);
        smemA[ph64(c4 * 4 + 1, dv)] = f2bf(v.y);
        smemA[ph64(c4 * 4 + 2, dv)] = f2bf(v.z);
        smemA[ph64(c4 * 4 + 3, dv)] = f2bf(v.w);
    }
    __syncthreads();

    // ---- out-proj: D[c][q] = WoT(c,dv) @ O^T(dv,q); C layout -> q-coalesced
    const float gm = gma[0];
#pragma unroll
    for (int mt = 0; mt < 8; ++mt) {
        f32x4 D = (f32x4){0.f, 0.f, 0.f, 0.f};
#pragma unroll
        for (int ks = 0; ks < 2; ++ks) {
            const short8 af = *(const short8*)&smemA[ph64(mt * 16 + lm, ks * 32 + g * 8)];
            const short8 bf = *(const short8*)&Ol[ph64(lm, ks * 32 + g * 8)];
            D = __builtin_amdgcn_mfma_f32_16x16x32_bf16(af, bf, D, 0, 0, 0);
        }
#pragma unroll
        for (int r = 0; r < 4; ++r) {
            const int c = mt * 16 + g * 4 + r;
            const size_t off = ((size_t)n * CC + c) * HWN + q0b + w * 16 + lm;
            out[off] = x[off] + gm * (D[r] + bo[c]);
        }
    }
}

extern "C" void kernel_launch(void* const* d_in, const int* in_sizes, int n_in,
                              void* d_out, int out_size, void* d_ws, size_t ws_size,
                              hipStream_t stream) {
    const float* x     = (const float*)d_in[0];
    const float* Wq    = (const float*)d_in[1];
    const float* bq    = (const float*)d_in[2];
    const float* Wk    = (const float*)d_in[3];
    const float* bk    = (const float*)d_in[4];
    const float* Wv    = (const float*)d_in[5];
    const float* bv    = (const float*)d_in[6];
    const float* Wo    = (const float*)d_in[7];
    const float* bo    = (const float*)d_in[8];
    const float* gamma = (const float*)d_in[9];
    float* out = (float*)d_out;

    u16* Qp = (u16*)d_ws;                          // 8*4096*16 bf16 = 1 MB
    u16* Kp = Qp + (size_t)NB * HWN * AD;          // 8*1024*16 bf16 = 256 KB
    u16* Vt = Kp + (size_t)NB * PJ * AD;           // 8*64*1024 bf16 = 1 MB

    k_proj<<<dim3(32, NB), 256, 0, stream>>>(x, Wq, bq, Wk, bk, Wv, bv, Qp, Kp, Vt);
    k_attn<<<dim3(64, NB), 256, 0, stream>>>(x, Qp, Kp, Vt, Wo, bo, gamma, out);
}